// Round 4
// baseline (293.112 us; speedup 1.0000x reference)
//
#include <hip/hip_runtime.h>
#include <cstddef>

// Problem constants (from reference)
#define NIMG   3
#define NSEQ   64
#define C_TOT  512
#define HH     22
#define WW     22
#define FS     4          // FILTER_SIZE (pooled size)
#define CB     16         // channels per block
#define SCALE  (1.0f/16.0f)  // 1/FEATURE_STRIDE

__device__ __forceinline__ float hat_cdf(float t) {
    // Antiderivative of hat psi(x)=max(0,1-|x|)
    if (t <= -1.0f) return 0.0f;
    if (t <= 0.0f)  { float u = t + 1.0f; return 0.5f * u * u; }
    if (t <= 1.0f)  return 0.5f + t - 0.5f * t * t;
    return 1.0f;
}

__global__ __launch_bounds__(256) void prroi_filter_init_kernel(
    const float* __restrict__ feat,   // (NIMG, NSEQ, C, H, W)
    const float* __restrict__ bb,     // (NIMG, NSEQ, 4) as (x,y,w,h)
    float* __restrict__ out)          // (NSEQ, C, FS, FS)
{
    const int s    = blockIdx.x;        // sequence index 0..63
    const int cblk = blockIdx.y;        // channel block 0..31
    const int c0   = cblk * CB;

    __shared__ float sXw[NIMG][FS][WW];   // x-direction hat integrals
    __shared__ float sYc[NIMG][FS][HH];   // y-direction hat integrals * coef (area,mean,norm folded)
    __shared__ float sOut[CB][FS * FS];

    const int t = threadIdx.x;

    // ---- precompute per-image pooling weights into LDS ----
    const int NENT = NIMG * FS * (WW + HH);   // 528
    for (int e = t; e < NENT; e += 256) {
        const int i   = e / (FS * (WW + HH));
        const int rem = e % (FS * (WW + HH));
        const int q   = rem / (WW + HH);
        const int k   = rem % (WW + HH);
        const float bx = bb[((size_t)i * NSEQ + s) * 4 + 0] * SCALE;
        const float by = bb[((size_t)i * NSEQ + s) * 4 + 1] * SCALE;
        const float bw = bb[((size_t)i * NSEQ + s) * 4 + 2] * SCALE;
        const float bh = bb[((size_t)i * NSEQ + s) * 4 + 3] * SCALE;
        const float bin_w = bw * (1.0f / FS);
        const float bin_h = bh * (1.0f / FS);
        if (k < WW) {
            const float sx = bx + q * bin_w;
            const float ex = sx + bin_w;
            sXw[i][q][k] = hat_cdf(ex - (float)k) - hat_cdf(sx - (float)k);
        } else {
            const int hh = k - WW;
            const float area = fmaxf(bin_w * bin_h, 0.0f);
            // fold: /area (PrRoI), /NIMG (mean over images), /(C*FS*FS) (FILTER_NORM)
            const float coef = (area > 0.0f)
                ? 1.0f / (area * (float)NIMG * (float)(C_TOT * FS * FS))
                : 0.0f;
            const float sy = by + q * bin_h;
            const float ey = sy + bin_h;
            sYc[i][q][hh] = (hat_cdf(ey - (float)hh) - hat_cdf(sy - (float)hh)) * coef;
        }
    }
    __syncthreads();

    // ---- main accumulation: 16 lanes per channel, stride over 66 (i,h) rows ----
    const int c_local = t >> 4;       // 0..15
    const int sub     = t & 15;       // 0..15
    const int c       = c0 + c_local;

    float acc[FS][FS];
    #pragma unroll
    for (int p = 0; p < FS; ++p)
        #pragma unroll
        for (int q = 0; q < FS; ++q) acc[p][q] = 0.0f;

    for (int r = sub; r < NIMG * HH; r += 16) {
        const int i = r / HH;
        const int h = r % HH;
        const float* rowp = feat +
            ((((size_t)i * NSEQ + s) * C_TOT + c) * HH + h) * WW;

        float row[WW];
        const float2* rp2 = (const float2*)rowp;   // rows are 8B-aligned (88B pitch)
        #pragma unroll
        for (int j = 0; j < WW / 2; ++j) {
            float2 v = rp2[j];
            row[2 * j]     = v.x;
            row[2 * j + 1] = v.y;
        }

        float rpool[FS];
        #pragma unroll
        for (int q = 0; q < FS; ++q) {
            float sum = 0.0f;
            #pragma unroll
            for (int w = 0; w < WW; ++w) sum += sXw[i][q][w] * row[w];
            rpool[q] = sum;
        }
        #pragma unroll
        for (int p = 0; p < FS; ++p) {
            const float yc = sYc[i][p][h];
            #pragma unroll
            for (int q = 0; q < FS; ++q) acc[p][q] += yc * rpool[q];
        }
    }

    // ---- reduce across the 16 lanes of each channel group ----
    #pragma unroll
    for (int off = 8; off >= 1; off >>= 1) {
        #pragma unroll
        for (int p = 0; p < FS; ++p)
            #pragma unroll
            for (int q = 0; q < FS; ++q)
                acc[p][q] += __shfl_xor(acc[p][q], off, 64);
    }

    if (sub == 0) {
        #pragma unroll
        for (int p = 0; p < FS; ++p)
            #pragma unroll
            for (int q = 0; q < FS; ++q)
                sOut[c_local][p * FS + q] = acc[p][q];
    }
    __syncthreads();

    // ---- coalesced 256-float store: out[s][c0..c0+16)[p][q] ----
    out[((size_t)s * C_TOT + c0) * (FS * FS) + t] = sOut[t >> 4][t & 15];
}

extern "C" void kernel_launch(void* const* d_in, const int* in_sizes, int n_in,
                              void* d_out, int out_size, void* d_ws, size_t ws_size,
                              hipStream_t stream) {
    const float* feat = (const float*)d_in[0];   // 3*64*512*22*22
    const float* bb   = (const float*)d_in[1];   // 3*64*4
    float* out        = (float*)d_out;           // 64*512*4*4

    dim3 grid(NSEQ, C_TOT / CB);   // (64, 32)
    dim3 block(256);
    prroi_filter_init_kernel<<<grid, block, 0, stream>>>(feat, bb, out);
}